// Round 11
// baseline (72.196 us; speedup 1.0000x reference)
//
#include <hip/hip_runtime.h>
#include <math.h>

#define NE 64
#define ND 512
#define NH 1024
#define NT 256
#define NC 8   // fc1 token chunk (= pad amount in build_group)
#define NC2 4  // fc2 token chunk

// ws layout: h[NT*NH] floats

__device__ __forceinline__ int build_group(const int* __restrict__ idx, int e,
                                           int* tok_lds, int* wsum) {
    const int t = threadIdx.x, wave = t >> 6, lane = t & 63;
    const bool m = (idx[t] == e);
    const unsigned long long mask = __ballot(m);
    if (lane == 0) wsum[wave] = __popcll(mask);
    __syncthreads();
    int before = 0;
#pragma unroll
    for (int w = 0; w < 3; ++w) before += (w < wave) ? wsum[w] : 0;
    const int nt = wsum[0] + wsum[1] + wsum[2] + wsum[3];
    if (m) {
        int pos = before + __popcll(mask & ((1ull << lane) - 1ull));
        tok_lds[pos] = t;
    }
    __syncthreads();
    // pad so fragment loads are unconditional (dupes of token 0; stores stay
    // guarded by nt, so pad results are discarded)
    if (nt > 0 && t >= nt && t < nt + NC) tok_lds[t] = tok_lds[0];
    __syncthreads();
    return nt;
}

// Fused butterfly over 8 accumulators: 10 shuffles, depth 6, for 8 full
// 64-lane reductions. On exit lanes 0..7 hold the sum for token bitrev3(lane).
__device__ __forceinline__ float fused_reduce8_64(float v[NC], int lane) {
#pragma unroll
    for (int i = 0; i < 4; ++i) {
        float lo = v[i], hi = v[i + 4];
        float send = (lane & 1) ? lo : hi;
        float recv = __shfl_xor(send, 1);
        v[i] = ((lane & 1) ? hi : lo) + recv;
    }
#pragma unroll
    for (int i = 0; i < 2; ++i) {
        float lo = v[i], hi = v[i + 2];
        float send = (lane & 2) ? lo : hi;
        float recv = __shfl_xor(send, 2);
        v[i] = ((lane & 2) ? hi : lo) + recv;
    }
    {
        float lo = v[0], hi = v[1];
        float send = (lane & 4) ? lo : hi;
        float recv = __shfl_xor(send, 4);
        v[0] = ((lane & 4) ? hi : lo) + recv;
    }
    v[0] += __shfl_xor(v[0], 8);
    v[0] += __shfl_xor(v[0], 16);
    v[0] += __shfl_xor(v[0], 32);
    return v[0];
}

// Fused butterfly over 4 accumulators -> full 64-lane sums.
// On exit lane l holds the sum for token t = 2*(l&1) + ((l>>1)&1).
__device__ __forceinline__ float fused_reduce4_64(float v[4], int lane) {
#pragma unroll
    for (int i = 0; i < 2; ++i) {
        float lo = v[i], hi = v[i + 2];
        float send = (lane & 1) ? lo : hi;
        float recv = __shfl_xor(send, 1);
        v[i] = ((lane & 1) ? hi : lo) + recv;
    }
    {
        float lo = v[0], hi = v[1];
        float send = (lane & 2) ? lo : hi;
        float recv = __shfl_xor(send, 2);
        v[0] = ((lane & 2) ? hi : lo) + recv;
    }
    v[0] += __shfl_xor(v[0], 4);
    v[0] += __shfl_xor(v[0], 8);
    v[0] += __shfl_xor(v[0], 16);
    v[0] += __shfl_xor(v[0], 32);
    return v[0];
}

// fc1: grid = NE*32. 2-wave K-teams: team = wave>>1 owns 16 H-rows; within a
// team, half = wave&1 covers K-slice [half*256, half*256+256). Per-lane x
// state = 8 tokens x 1 float4 = 32 VGPR -> fragments PROVABLY fit in regs at
// 8 waves/SIMD (launch_bounds(256,8)); inner loop has zero reload traffic:
// 1 coalesced weight load + 32 FMA + butterfly per row. Halves combine via a
// 2KB LDS partial buffer once per token chunk.
__global__ __launch_bounds__(256, 8) void fc1_kernel(
    const float* __restrict__ x, const float* __restrict__ w1,
    const int* __restrict__ idx, float* __restrict__ h) {
    __shared__ int tok_lds[NT + NC];
    __shared__ int wsum[4];
    __shared__ float part[2][2][16][NC];   // [team][half][row][token] 2 KB
    const int e  = blockIdx.x >> 5;
    const int ch = blockIdx.x & 31;
    const int tid = threadIdx.x, wave = tid >> 6, lane = tid & 63;
    const int team = wave >> 1, half = wave & 1;
    const int nt = build_group(idx, e, tok_lds, wsum);
    if (nt == 0) return;
    const float* w1e = w1 + (size_t)e * NH * ND;
    const int jb = ch * 32 + team * 16;       // team's 16 rows
    const int kb = half * 256 + lane * 4;     // this wave's K-slice base

    for (int base = 0; base < nt; base += NC) {
        float4 xs[NC];
#pragma unroll
        for (int t = 0; t < NC; ++t)
            xs[t] = *(const float4*)(x + (size_t)tok_lds[base + t] * ND + kb);

#pragma unroll 4
        for (int r = 0; r < 16; ++r) {
            const float4 wv = *(const float4*)(w1e + (size_t)(jb + r) * ND + kb);
            float acc[NC];
#pragma unroll
            for (int t = 0; t < NC; ++t)
                acc[t] = wv.x * xs[t].x + wv.y * xs[t].y
                       + wv.z * xs[t].z + wv.w * xs[t].w;
            float p = fused_reduce8_64(acc, lane);
            if (lane < NC) {
                int t = ((lane & 1) << 2) | (lane & 2) | ((lane >> 2) & 1);
                part[team][half][r][t] = p;
            }
        }
        __syncthreads();   // partials complete
        {   // combine halves: 2 teams x 16 rows x 8 tokens = 256 threads.
            // mapping: token slow, row fast -> 64B-contiguous h stores
            const int cteam = tid >> 7, ct = (tid >> 4) & 7, cr = tid & 15;
            if (base + ct < nt) {
                float s = part[cteam][0][cr][ct] + part[cteam][1][cr][ct];
                s = s / (1.0f + __expf(-s));
                int tk = tok_lds[base + ct];
                h[(size_t)tk * NH + (ch * 32 + cteam * 16 + cr)] = s;
            }
        }
        __syncthreads();   // protect part from next pass's writes
    }
}

// fc2: grid = NE*32. Same 2-wave K-team structure: team owns 8 D-rows; half
// covers K-slice [half*512, half*512+512) as two float4 per token. Per-lane
// h state = 4 tokens x 2 float4 = 32 VGPR.
__global__ __launch_bounds__(256, 8) void fc2_kernel(
    const float* __restrict__ h, const float* __restrict__ w2,
    const int* __restrict__ idx, float* __restrict__ out) {
    __shared__ int tok_lds[NT + NC];
    __shared__ int wsum[4];
    __shared__ float part2[2][2][8][NC2];  // [team][half][row][token] 512 B
    const int e  = blockIdx.x >> 5;
    const int ch = blockIdx.x & 31;
    const int tid = threadIdx.x, wave = tid >> 6, lane = tid & 63;
    const int team = wave >> 1, half = wave & 1;
    const int nt = build_group(idx, e, tok_lds, wsum);
    if (nt == 0) return;
    const float* w2e = w2 + (size_t)e * ND * NH;
    const int db = ch * 16 + team * 8;        // team's 8 rows
    const int kb = half * 512 + lane * 4;     // K-slice base (+256 for 2nd frag)

    for (int base = 0; base < nt; base += NC2) {
        float4 ha[NC2], hb[NC2];
#pragma unroll
        for (int t = 0; t < NC2; ++t) {
            const float* hr = h + (size_t)tok_lds[base + t] * NH;
            ha[t] = *(const float4*)(hr + kb);
            hb[t] = *(const float4*)(hr + kb + 256);
        }

#pragma unroll 4
        for (int r = 0; r < 8; ++r) {
            const float* wr = w2e + (size_t)(db + r) * NH;
            const float4 wa = *(const float4*)(wr + kb);
            const float4 wb = *(const float4*)(wr + kb + 256);
            float acc[NC2];
#pragma unroll
            for (int t = 0; t < NC2; ++t)
                acc[t] = wa.x * ha[t].x + wa.y * ha[t].y
                       + wa.z * ha[t].z + wa.w * ha[t].w
                       + wb.x * hb[t].x + wb.y * hb[t].y
                       + wb.z * hb[t].z + wb.w * hb[t].w;
            float p = fused_reduce4_64(acc, lane);
            if (lane < NC2) {
                int t = ((lane & 1) << 1) | ((lane >> 1) & 1);
                part2[team][half][r][t] = p;
            }
        }
        __syncthreads();
        if (tid < 64) {   // 2 teams x 8 rows x 4 tokens; row-fast mapping
            const int cteam = tid >> 5, ct = (tid >> 3) & 3, cr = tid & 7;
            if (base + ct < nt) {
                float s = part2[cteam][0][cr][ct] + part2[cteam][1][cr][ct];
                int tk = tok_lds[base + ct];
                out[(size_t)tk * ND + (ch * 16 + cteam * 8 + cr)] = s;
            }
        }
        __syncthreads();
    }
}

extern "C" void kernel_launch(void* const* d_in, const int* in_sizes, int n_in,
                              void* d_out, int out_size, void* d_ws, size_t ws_size,
                              hipStream_t stream) {
    const float* x    = (const float*)d_in[0];
    const int*   eidx = (const int*)d_in[1];
    const float* fc1w = (const float*)d_in[2];
    const float* fc2w = (const float*)d_in[3];
    float* out = (float*)d_out;
    float* h   = (float*)d_ws;

    fc1_kernel<<<NE * 32, 256, 0, stream>>>(x, fc1w, eidx, h);
    fc2_kernel<<<NE * 32, 256, 0, stream>>>(h, fc2w, eidx, out);
}